// Round 1
// baseline (2783.401 us; speedup 1.0000x reference)
//
#include <hip/hip_runtime.h>
#include <math.h>

#define N_TOK 4096
#define C_DIM 256
#define G_DIM 31
#define E_DIM 32
#define H_DIM 1024
#define TT    16

// ---------------- gate kernel: 1 block (256 thr) per token ----------------
__global__ __launch_bounds__(256) void gate_kernel(
    const float* __restrict__ xf, const float* __restrict__ rfp,
    const float* __restrict__ Wg, const float* __restrict__ bg,
    const float* __restrict__ ebias,
    float* __restrict__ rw_out, int* __restrict__ counts,
    int* __restrict__ btok, float* __restrict__ bwgt,
    float* __restrict__ ref2_out)
{
    const int tok = blockIdx.x;
    const int j = threadIdx.x;
    __shared__ __align__(16) float xs[C_DIM];
    __shared__ float lg[G_DIM];
    __shared__ float wred[4];

    float xv = xf[(size_t)tok * C_DIM + j];
    xs[j] = xv;
    float rv = rfp[(size_t)tok * C_DIM + j];
    float r2 = rv * rv;
    #pragma unroll
    for (int off = 32; off; off >>= 1) r2 += __shfl_down(r2, off);
    if ((j & 63) == 0) wred[j >> 6] = r2;
    __syncthreads();

    // logits: 8 threads per gate output
    const int g = j >> 3, sub = j & 7;
    if (g < G_DIM) {
        float acc = 0.f;
        for (int c = sub; c < C_DIM; c += 8)
            acc += xs[c] * Wg[c * G_DIM + g];
        acc += __shfl_down(acc, 4);
        acc += __shfl_down(acc, 2);
        acc += __shfl_down(acc, 1);
        if (sub == 0) lg[g] = acc + bg[g];
    }
    __syncthreads();

    if (j == 0) {
        float ref2 = wred[0] + wred[1] + wred[2] + wred[3];
        ref2_out[tok] = ref2;

        float m = lg[0];
        #pragma unroll
        for (int g2 = 1; g2 < G_DIM; ++g2) m = fmaxf(m, lg[g2]);
        float p[G_DIM];
        float s = 0.f;
        #pragma unroll
        for (int g2 = 0; g2 < G_DIM; ++g2) { p[g2] = __expf(lg[g2] - m); s += p[g2]; }
        float inv = 1.f / s;
        float bi[G_DIM];
        #pragma unroll
        for (int g2 = 0; g2 < G_DIM; ++g2) bi[g2] = p[g2] * inv + ebias[g2];

        int   idx[3];
        float val[3];
        #pragma unroll
        for (int t = 0; t < 3; ++t) {
            int   bidx = 0;
            float bv = -1e30f;
            for (int g2 = 0; g2 < G_DIM; ++g2)
                if (bi[g2] > bv) { bv = bi[g2]; bidx = g2; }
            idx[t] = bidx; val[t] = bv; bi[bidx] = -1e30f;
        }
        float vs = val[0] + val[1] + val[2];
        float w[3];
        #pragma unroll
        for (int t = 0; t < 3; ++t) w[t] = (val[t] / vs) * 0.75f;

        float r32[E_DIM];
        #pragma unroll
        for (int e = 0; e < E_DIM; ++e) r32[e] = 0.f;
        r32[0] = 0.25f;
        #pragma unroll
        for (int t = 0; t < 3; ++t) r32[idx[t] + 1] = w[t];
        for (int e = 0; e < E_DIM; ++e) rw_out[(size_t)tok * E_DIM + e] = r32[e];

        int slot = atomicAdd(&counts[0], 1);
        btok[slot] = tok; bwgt[slot] = 0.25f;
        #pragma unroll
        for (int t = 0; t < 3; ++t) {
            int e = idx[t] + 1;
            slot = atomicAdd(&counts[e], 1);
            btok[(size_t)e * N_TOK + slot] = tok;
            bwgt[(size_t)e * N_TOK + slot] = w[t];
        }
    }
}

// ---------------- expert kernel: tile of TT tokens for one expert ----------------
__global__ __launch_bounds__(256) void expert_kernel(
    const float* __restrict__ xf, const float* __restrict__ rfp,
    const float* __restrict__ Wfc, const float* __restrict__ bfc,
    const float* __restrict__ Wproj, const float* __restrict__ bproj,
    const float* __restrict__ cptr, const float* __restrict__ ref2p,
    const int* __restrict__ counts, const int* __restrict__ btok,
    const float* __restrict__ bwgt, float* __restrict__ out)
{
    const int e = blockIdx.x;
    const int cnt = counts[e];
    const int base = blockIdx.y * TT;
    if (base >= cnt) return;
    const int nt = min(TT, cnt - base);
    const int j = threadIdx.x;

    __shared__ __align__(16) float xs[TT * C_DIM];   // 16 KB
    __shared__ __align__(16) float hs[TT * C_DIM];   // 16 KB (staging, then y)
    __shared__ int   stok[TT];
    __shared__ float swgt[TT];
    __shared__ float scA[TT], scB[TT];

    if (j < nt) {
        stok[j] = btok[(size_t)e * N_TOK + base + j];
        swgt[j] = bwgt[(size_t)e * N_TOK + base + j];
    }
    __syncthreads();
    for (int t = 0; t < nt; ++t) xs[t * C_DIM + j] = xf[(size_t)stok[t] * C_DIM + j];
    for (int t = nt; t < TT; ++t) xs[t * C_DIM + j] = 0.f;
    __syncthreads();

    // ---- phase 1: h = gelu(x @ Wfc + bfc); thread j owns hh = j + 256k ----
    const float* Wfc_e = Wfc + (size_t)e * C_DIM * H_DIM;
    float h[4][TT];
    {
        float bk[4];
        #pragma unroll
        for (int k = 0; k < 4; ++k) bk[k] = bfc[(size_t)e * H_DIM + j + k * 256];
        #pragma unroll
        for (int k = 0; k < 4; ++k)
            #pragma unroll
            for (int tt = 0; tt < TT; ++tt) h[k][tt] = bk[k];
    }
    for (int c0 = 0; c0 < C_DIM; c0 += 4) {
        float w[4][4];
        #pragma unroll
        for (int ci = 0; ci < 4; ++ci) {
            const float* wp = Wfc_e + (size_t)(c0 + ci) * H_DIM + j;
            w[ci][0] = wp[0]; w[ci][1] = wp[256]; w[ci][2] = wp[512]; w[ci][3] = wp[768];
        }
        #pragma unroll
        for (int tt = 0; tt < TT; ++tt) {
            float4 xv = *(const float4*)(xs + tt * C_DIM + c0);
            #pragma unroll
            for (int k = 0; k < 4; ++k)
                h[k][tt] += xv.x * w[0][k] + xv.y * w[1][k] + xv.z * w[2][k] + xv.w * w[3][k];
        }
    }
    #pragma unroll
    for (int k = 0; k < 4; ++k)
        #pragma unroll
        for (int tt = 0; tt < TT; ++tt) {
            float v = h[k][tt];
            h[k][tt] = 0.5f * v * (1.f + erff(v * 0.70710678118f));
        }

    // ---- phase 2: y = h @ Wproj + bproj; thread j owns output col j ----
    const float* Wp_e = Wproj + (size_t)e * H_DIM * C_DIM;
    float yacc[TT];
    {
        float bp = bproj[(size_t)e * C_DIM + j];
        #pragma unroll
        for (int tt = 0; tt < TT; ++tt) yacc[tt] = bp;
    }
    #pragma unroll
    for (int k = 0; k < 4; ++k) {
        __syncthreads();
        #pragma unroll
        for (int tt = 0; tt < TT; ++tt) hs[tt * C_DIM + j] = h[k][tt];
        __syncthreads();
        for (int h0 = 0; h0 < 256; h0 += 4) {
            float w[4];
            #pragma unroll
            for (int hi = 0; hi < 4; ++hi)
                w[hi] = Wp_e[(size_t)(k * 256 + h0 + hi) * C_DIM + j];
            #pragma unroll
            for (int tt = 0; tt < TT; ++tt) {
                float4 hv = *(const float4*)(hs + tt * C_DIM + h0);
                yacc[tt] += hv.x * w[0] + hv.y * w[1] + hv.z * w[2] + hv.w * w[3];
            }
        }
    }

    // stash y in LDS
    __syncthreads();
    #pragma unroll
    for (int tt = 0; tt < TT; ++tt) hs[tt * C_DIM + j] = yacc[tt];
    __syncthreads();

    // ---- phase 3: expmap coefficients (one wave handles 4 tokens) ----
    const float cc0 = cptr[0];
    const int wave = j >> 6, lane = j & 63;
    for (int q = 0; q < 4; ++q) {
        int tt = wave * 4 + q;
        if (tt >= nt) break;
        int tok = stok[tt];
        float s2 = 0.f, sxy = 0.f;
        #pragma unroll
        for (int m = 0; m < 4; ++m) {
            int ccol = lane + 64 * m;
            float yv = hs[tt * C_DIM + ccol];
            float rv = rfp[(size_t)tok * C_DIM + ccol];
            s2 += yv * yv; sxy += rv * yv;
        }
        #pragma unroll
        for (int off = 32; off; off >>= 1) {
            s2  += __shfl_down(s2, off);
            sxy += __shfl_down(sxy, off);
        }
        if (lane == 0) {
            float ref2 = ref2p[tok];
            float sf = 2.f / (1.f + cc0 * ref2);
            float vn = sqrtf(s2);
            float a = sqrtf(cc0 * sf * 0.5f);
            float alpha = (vn > 1e-20f)
                        ? (tanhf(a * vn) / (vn * sqrtf(cc0)))
                        : (a / sqrtf(cc0));
            float axy = alpha * sxy;
            float ay2 = alpha * alpha * s2;
            float A   = 1.f + 2.f * cc0 * axy + cc0 * ay2;
            float Bc  = (1.f - cc0 * ref2) * alpha;
            float den = 1.f + 2.f * cc0 * axy + cc0 * cc0 * ref2 * ay2;
            float wi  = swgt[tt] / den;
            scA[tt] = A * wi;
            scB[tt] = Bc * wi;
        }
    }
    __syncthreads();

    // ---- weighted expmap output, atomic accumulate ----
    for (int tt = 0; tt < nt; ++tt) {
        int tok = stok[tt];
        float rv = rfp[(size_t)tok * C_DIM + j];
        float yv = hs[tt * C_DIM + j];
        atomicAdd(&out[(size_t)tok * C_DIM + j], scA[tt] * rv + scB[tt] * yv);
    }
}

extern "C" void kernel_launch(void* const* d_in, const int* in_sizes, int n_in,
                              void* d_out, int out_size, void* d_ws, size_t ws_size,
                              hipStream_t stream) {
    const float* x     = (const float*)d_in[0];
    const float* rfp   = (const float*)d_in[1];
    const float* Wg    = (const float*)d_in[2];
    const float* bg    = (const float*)d_in[3];
    const float* ebias = (const float*)d_in[4];
    const float* Wfc   = (const float*)d_in[5];
    const float* bfc   = (const float*)d_in[6];
    const float* Wproj = (const float*)d_in[7];
    const float* bproj = (const float*)d_in[8];
    const float* cptr  = (const float*)d_in[9];

    float* out = (float*)d_out;                       // [n, C]
    float* rw  = out + (size_t)N_TOK * C_DIM;         // [n, E]

    char* ws = (char*)d_ws;
    int*   counts = (int*)ws;                                       // 32 ints
    int*   btok   = (int*)(ws + 128);                               // 32*4096 ints
    float* bwgt   = (float*)(ws + 128 + (size_t)E_DIM * N_TOK * 4); // 32*4096 floats
    float* ref2   = (float*)(ws + 128 + (size_t)E_DIM * N_TOK * 8); // 4096 floats

    hipMemsetAsync(counts, 0, E_DIM * sizeof(int), stream);
    hipMemsetAsync(out, 0, (size_t)N_TOK * C_DIM * sizeof(float), stream);

    gate_kernel<<<N_TOK, 256, 0, stream>>>(x, rfp, Wg, bg, ebias,
                                           rw, counts, btok, bwgt, ref2);

    dim3 grid(E_DIM, N_TOK / TT);
    expert_kernel<<<grid, 256, 0, stream>>>(x, rfp, Wfc, bfc, Wproj, bproj,
                                            cptr, ref2, counts, btok, bwgt, out);
}

// Round 2
// 492.489 us; speedup vs baseline: 5.6517x; 5.6517x over previous
//
#include <hip/hip_runtime.h>
#include <math.h>

#define N_TOK 4096
#define C_DIM 256
#define G_DIM 31
#define E_DIM 32
#define H_DIM 1024
#define TT    16   // fallback tile (round-1 kernel)
#define MT    32   // mfma tile tokens

typedef unsigned short ushort_t;
typedef unsigned int uint_t;
typedef __attribute__((ext_vector_type(8))) short bfrag;
typedef __attribute__((ext_vector_type(4))) float f32x4;
typedef __attribute__((ext_vector_type(8))) unsigned short ushort8;

__device__ __forceinline__ ushort_t f2bf(float f) {
    uint_t u = __float_as_uint(f);
    uint_t r = (u + 0x7fffu + ((u >> 16) & 1u)) >> 16;
    return (ushort_t)r;
}

__device__ __forceinline__ float gelu_f(float v) {
    // tanh-approx gelu; error <=~1e-3 abs, below bf16 quantization noise here
    float u = 0.7978845608f * fmaf(0.044715f * v * v, v, v);
    float t = __expf(-2.f * u);
    return 0.5f * v * (1.f + (1.f - t) / (1.f + t));
}

// ---------------- gate kernel: 1 block (256 thr) per token (unchanged, proven) ----------------
__global__ __launch_bounds__(256) void gate_kernel(
    const float* __restrict__ xf, const float* __restrict__ rfp,
    const float* __restrict__ Wg, const float* __restrict__ bg,
    const float* __restrict__ ebias,
    float* __restrict__ rw_out, int* __restrict__ counts,
    int* __restrict__ btok, float* __restrict__ bwgt,
    float* __restrict__ ref2_out)
{
    const int tok = blockIdx.x;
    const int j = threadIdx.x;
    __shared__ __align__(16) float xs[C_DIM];
    __shared__ float lg[G_DIM];
    __shared__ float wred[4];

    float xv = xf[(size_t)tok * C_DIM + j];
    xs[j] = xv;
    float rv = rfp[(size_t)tok * C_DIM + j];
    float r2 = rv * rv;
    #pragma unroll
    for (int off = 32; off; off >>= 1) r2 += __shfl_down(r2, off);
    if ((j & 63) == 0) wred[j >> 6] = r2;
    __syncthreads();

    const int g = j >> 3, sub = j & 7;
    if (g < G_DIM) {
        float acc = 0.f;
        for (int c = sub; c < C_DIM; c += 8)
            acc += xs[c] * Wg[c * G_DIM + g];
        acc += __shfl_down(acc, 4);
        acc += __shfl_down(acc, 2);
        acc += __shfl_down(acc, 1);
        if (sub == 0) lg[g] = acc + bg[g];
    }
    __syncthreads();

    if (j == 0) {
        float ref2 = wred[0] + wred[1] + wred[2] + wred[3];
        ref2_out[tok] = ref2;

        float m = lg[0];
        #pragma unroll
        for (int g2 = 1; g2 < G_DIM; ++g2) m = fmaxf(m, lg[g2]);
        float p[G_DIM];
        float s = 0.f;
        #pragma unroll
        for (int g2 = 0; g2 < G_DIM; ++g2) { p[g2] = __expf(lg[g2] - m); s += p[g2]; }
        float inv = 1.f / s;
        float bi[G_DIM];
        #pragma unroll
        for (int g2 = 0; g2 < G_DIM; ++g2) bi[g2] = p[g2] * inv + ebias[g2];

        int   idx[3];
        float val[3];
        #pragma unroll
        for (int t = 0; t < 3; ++t) {
            int   bidx = 0;
            float bv = -1e30f;
            for (int g2 = 0; g2 < G_DIM; ++g2)
                if (bi[g2] > bv) { bv = bi[g2]; bidx = g2; }
            idx[t] = bidx; val[t] = bv; bi[bidx] = -1e30f;
        }
        float vs = val[0] + val[1] + val[2];
        float w[3];
        #pragma unroll
        for (int t = 0; t < 3; ++t) w[t] = (val[t] / vs) * 0.75f;

        float r32[E_DIM];
        #pragma unroll
        for (int e = 0; e < E_DIM; ++e) r32[e] = 0.f;
        r32[0] = 0.25f;
        #pragma unroll
        for (int t = 0; t < 3; ++t) r32[idx[t] + 1] = w[t];
        for (int e = 0; e < E_DIM; ++e) rw_out[(size_t)tok * E_DIM + e] = r32[e];

        int slot = atomicAdd(&counts[0], 1);
        btok[slot] = tok; bwgt[slot] = 0.25f;
        #pragma unroll
        for (int t = 0; t < 3; ++t) {
            int e = idx[t] + 1;
            slot = atomicAdd(&counts[e], 1);
            btok[(size_t)e * N_TOK + slot] = tok;
            bwgt[(size_t)e * N_TOK + slot] = w[t];
        }
    }
}

// ---------------- weight transform: fp32 -> bf16 fragment-linear blocks ----------------
// Wfc frag block id = e*512 + kt*64 + nt   (kt: K=C 8x32, nt: N=H 64x16)
// Wproj frag block id = e*512 + kt*16 + nt (kt: K=H 32x32, nt: N=C 16x16)
// Within a block: lane*8 bf16 elems = B[k0+(lane>>4)*8+j][n0+(lane&15)], j=0..7
__global__ __launch_bounds__(256) void wtrans_kernel(
    const float* __restrict__ Wfc, const float* __restrict__ Wproj,
    ushort_t* __restrict__ WfcF, ushort_t* __restrict__ WprojF)
{
    int fb = blockIdx.x * 4 + (threadIdx.x >> 6);
    int lane = threadIdx.x & 63;
    ushort8 pv;
    if (fb < E_DIM * 8 * 64) {
        int e = fb >> 9, kt = (fb >> 6) & 7, nt = fb & 63;
        const float* src = Wfc + ((size_t)e << 18);
        int k0 = kt * 32 + (lane >> 4) * 8, n = nt * 16 + (lane & 15);
        #pragma unroll
        for (int j = 0; j < 8; ++j)
            pv[j] = f2bf(src[((size_t)(k0 + j) << 10) + n]);
        *(ushort8*)(WfcF + ((size_t)fb * 64 + lane) * 8) = pv;
    } else {
        int b2 = fb - E_DIM * 8 * 64;
        int e = b2 >> 9, kt = (b2 >> 4) & 31, nt = b2 & 15;
        const float* src = Wproj + ((size_t)e << 18);
        int k0 = kt * 32 + (lane >> 4) * 8, n = nt * 16 + (lane & 15);
        #pragma unroll
        for (int j = 0; j < 8; ++j)
            pv[j] = f2bf(src[((size_t)(k0 + j) << 8) + n]);
        *(ushort8*)(WprojF + ((size_t)b2 * 64 + lane) * 8) = pv;
    }
}

// ---------------- MFMA expert kernel: 32 tokens x 1 expert per block ----------------
__global__ __launch_bounds__(256) void expert_mfma(
    const float* __restrict__ xf, const float* __restrict__ rfp,
    const ushort_t* __restrict__ WfcF, const ushort_t* __restrict__ WprojF,
    const float* __restrict__ bfc, const float* __restrict__ bproj,
    const float* __restrict__ cptr, const float* __restrict__ ref2p,
    const int* __restrict__ counts, const int* __restrict__ btok,
    const float* __restrict__ bwgt, float* __restrict__ out)
{
    const int e = blockIdx.y;
    const int cnt = counts[e];
    const int base = blockIdx.x * MT;
    if (base >= cnt) return;
    const int ntk = min(MT, cnt - base);
    const int tid = threadIdx.x;
    const int lane = tid & 63;
    const int w = tid >> 6;

    __shared__ __align__(16) ushort_t hfrag[MT * H_DIM];  // exactly 64 KB

    // ---- stage x into phase-1 A-fragment layout in hfrag[0 .. 8192) ----
    {
        const int r  = tid >> 3;
        const int c0 = (tid & 7) * 32;
        const int mt = r >> 4, rr = r & 15;
        const int kt = c0 >> 5;
        const bool valid = (r < ntk);
        const int tok = btok[(size_t)e * N_TOK + (valid ? base + r : base)];
        const float* xrow = xf + (size_t)tok * C_DIM;
        #pragma unroll
        for (int q = 0; q < 4; ++q) {
            ushort8 pv;
            #pragma unroll
            for (int j = 0; j < 8; ++j) {
                float xv = valid ? xrow[c0 + q * 8 + j] : 0.f;
                pv[j] = f2bf(xv);
            }
            *(ushort8*)(hfrag + (size_t)((mt * 8 + kt) * 64 + (rr + 16 * q)) * 8) = pv;
        }
    }
    __syncthreads();

    // ---- preload A fragments (same for all waves) ----
    bfrag afr[2][8];
    #pragma unroll
    for (int mt = 0; mt < 2; ++mt)
        #pragma unroll
        for (int kt = 0; kt < 8; ++kt)
            afr[mt][kt] = *(const bfrag*)(hfrag + (size_t)((mt * 8 + kt) * 64 + lane) * 8);
    __syncthreads();

    // ---- phase 1: h = gelu(x @ Wfc + bfc), written as phase-2 A-frags ----
    {
        const ushort_t* wbase = WfcF + (size_t)e * 512 * 512;
        bfrag bcur[8], bnxt[8];
        {
            int n1g = w * 16;
            #pragma unroll
            for (int kt = 0; kt < 8; ++kt)
                bcur[kt] = *(const bfrag*)(wbase + (size_t)(kt * 64 + n1g) * 512 + lane * 8);
        }
        for (int n1 = 0; n1 < 16; ++n1) {
            const int n1gc = w * 16 + n1;
            if (n1 < 15) {
                #pragma unroll
                for (int kt = 0; kt < 8; ++kt)
                    bnxt[kt] = *(const bfrag*)(wbase + (size_t)(kt * 64 + n1gc + 1) * 512 + lane * 8);
            }
            const int hcol = n1gc * 16 + (lane & 15);
            const float bv = bfc[e * H_DIM + hcol];
            f32x4 acc0 = {bv, bv, bv, bv}, acc1 = {bv, bv, bv, bv};
            #pragma unroll
            for (int kt = 0; kt < 8; ++kt) {
                acc0 = __builtin_amdgcn_mfma_f32_16x16x32_bf16(afr[0][kt], bcur[kt], acc0, 0, 0, 0);
                acc1 = __builtin_amdgcn_mfma_f32_16x16x32_bf16(afr[1][kt], bcur[kt], acc1, 0, 0, 0);
            }
            const int jj   = hcol & 7;
            const int grp  = (hcol & 31) >> 3;
            const int kth  = hcol >> 5;
            const int rb   = (lane >> 4) * 4;
            #pragma unroll
            for (int mt = 0; mt < 2; ++mt) {
                f32x4 a = mt ? acc1 : acc0;
                #pragma unroll
                for (int r = 0; r < 4; ++r) {
                    float g = gelu_f(a[r]);
                    int lanep = (rb + r) + 16 * grp;
                    hfrag[(size_t)((mt * 32 + kth) * 64 + lanep) * 8 + jj] = f2bf(g);
                }
            }
            if (n1 < 15) {
                #pragma unroll
                for (int kt = 0; kt < 8; ++kt) bcur[kt] = bnxt[kt];
            }
        }
    }
    __syncthreads();

    // ---- phase 2: y = h @ Wproj + bproj ----
    f32x4 yac[2][4];
    #pragma unroll
    for (int mt = 0; mt < 2; ++mt)
        #pragma unroll
        for (int q = 0; q < 4; ++q) {
            int ccol = (w * 4 + q) * 16 + (lane & 15);
            float bv = bproj[e * C_DIM + ccol];
            yac[mt][q] = {bv, bv, bv, bv};
        }
    {
        const ushort_t* wbase = WprojF + (size_t)e * 512 * 512;
        #pragma unroll 2
        for (int kt = 0; kt < 32; ++kt) {
            bfrag a0 = *(const bfrag*)(hfrag + (size_t)((kt)      * 64 + lane) * 8);
            bfrag a1 = *(const bfrag*)(hfrag + (size_t)((32 + kt) * 64 + lane) * 8);
            #pragma unroll
            for (int q = 0; q < 4; ++q) {
                bfrag bf = *(const bfrag*)(wbase + (size_t)(kt * 16 + (w * 4 + q)) * 512 + lane * 8);
                yac[0][q] = __builtin_amdgcn_mfma_f32_16x16x32_bf16(a0, bf, yac[0][q], 0, 0, 0);
                yac[1][q] = __builtin_amdgcn_mfma_f32_16x16x32_bf16(a1, bf, yac[1][q], 0, 0, 0);
            }
        }
    }
    __syncthreads();

    // ---- write y (f32) into LDS natural layout [32][264] (reuse hfrag) ----
    float* ynat = (float*)hfrag;   // 32*264*4 = 33792 B <= 65536 B
    #pragma unroll
    for (int mt = 0; mt < 2; ++mt)
        #pragma unroll
        for (int q = 0; q < 4; ++q) {
            int ccol = (w * 4 + q) * 16 + (lane & 15);
            #pragma unroll
            for (int r = 0; r < 4; ++r) {
                int tok = mt * 16 + (lane >> 4) * 4 + r;
                ynat[tok * 264 + ccol] = yac[mt][q][r];
            }
        }
    __syncthreads();

    // ---- epilogue: expmap + weighted atomic accumulate ----
    {
        const int r  = tid >> 3;
        const int c0 = (tid & 7) * 32;
        const bool valid = r < ntk;
        const int slot = base + r;
        const int tok = btok[(size_t)e * N_TOK + (valid ? slot : base)];
        const float wgt = valid ? bwgt[(size_t)e * N_TOK + slot] : 0.f;
        const float* rrow = rfp + (size_t)tok * C_DIM;
        const float* yrow = ynat + r * 264;
        float s2 = 0.f, sxy = 0.f;
        #pragma unroll
        for (int cc = 0; cc < 32; ++cc) {
            float yv = yrow[c0 + cc];
            float rv = rrow[c0 + cc];
            s2  = fmaf(yv, yv, s2);
            sxy = fmaf(rv, yv, sxy);
        }
        s2 += __shfl_down(s2, 4);  sxy += __shfl_down(sxy, 4);
        s2 += __shfl_down(s2, 2);  sxy += __shfl_down(sxy, 2);
        s2 += __shfl_down(s2, 1);  sxy += __shfl_down(sxy, 1);
        float aco = 0.f, bco = 0.f;
        if ((tid & 7) == 0) {
            const float cc0 = cptr[0];
            float ref2 = ref2p[tok];
            float sf = 2.f / (1.f + cc0 * ref2);
            float vn = sqrtf(s2);
            float aa = sqrtf(cc0 * sf * 0.5f);
            float alpha = (vn > 1e-20f)
                        ? (tanhf(aa * vn) / (vn * sqrtf(cc0)))
                        : (aa / sqrtf(cc0));
            float axy = alpha * sxy;
            float ay2 = alpha * alpha * s2;
            float A   = 1.f + 2.f * cc0 * axy + cc0 * ay2;
            float Bc  = (1.f - cc0 * ref2) * alpha;
            float den = 1.f + 2.f * cc0 * axy + cc0 * cc0 * ref2 * ay2;
            float wi  = wgt / den;
            aco = A * wi; bco = Bc * wi;
        }
        aco = __shfl(aco, lane & 56);
        bco = __shfl(bco, lane & 56);
        float* orow = out + (size_t)tok * C_DIM;
        #pragma unroll
        for (int cc = 0; cc < 32; ++cc) {
            float v = fmaf(aco, rrow[c0 + cc], bco * yrow[c0 + cc]);
            atomicAdd(&orow[c0 + cc], v);
        }
    }
}

// ---------------- fallback fp32 expert kernel (round-1, proven) ----------------
__global__ __launch_bounds__(256) void expert_kernel(
    const float* __restrict__ xf, const float* __restrict__ rfp,
    const float* __restrict__ Wfc, const float* __restrict__ bfc,
    const float* __restrict__ Wproj, const float* __restrict__ bproj,
    const float* __restrict__ cptr, const float* __restrict__ ref2p,
    const int* __restrict__ counts, const int* __restrict__ btok,
    const float* __restrict__ bwgt, float* __restrict__ out)
{
    const int e = blockIdx.x;
    const int cnt = counts[e];
    const int base = blockIdx.y * TT;
    if (base >= cnt) return;
    const int nt = min(TT, cnt - base);
    const int j = threadIdx.x;

    __shared__ __align__(16) float xs[TT * C_DIM];
    __shared__ __align__(16) float hs[TT * C_DIM];
    __shared__ int   stok[TT];
    __shared__ float swgt[TT];
    __shared__ float scA[TT], scB[TT];

    if (j < nt) {
        stok[j] = btok[(size_t)e * N_TOK + base + j];
        swgt[j] = bwgt[(size_t)e * N_TOK + base + j];
    }
    __syncthreads();
    for (int t = 0; t < nt; ++t) xs[t * C_DIM + j] = xf[(size_t)stok[t] * C_DIM + j];
    for (int t = nt; t < TT; ++t) xs[t * C_DIM + j] = 0.f;
    __syncthreads();

    const float* Wfc_e = Wfc + (size_t)e * C_DIM * H_DIM;
    float h[4][TT];
    {
        float bk[4];
        #pragma unroll
        for (int k = 0; k < 4; ++k) bk[k] = bfc[(size_t)e * H_DIM + j + k * 256];
        #pragma unroll
        for (int k = 0; k < 4; ++k)
            #pragma unroll
            for (int tt = 0; tt < TT; ++tt) h[k][tt] = bk[k];
    }
    for (int c0 = 0; c0 < C_DIM; c0 += 4) {
        float wv[4][4];
        #pragma unroll
        for (int ci = 0; ci < 4; ++ci) {
            const float* wp = Wfc_e + (size_t)(c0 + ci) * H_DIM + j;
            wv[ci][0] = wp[0]; wv[ci][1] = wp[256]; wv[ci][2] = wp[512]; wv[ci][3] = wp[768];
        }
        #pragma unroll
        for (int tt = 0; tt < TT; ++tt) {
            float4 xv = *(const float4*)(xs + tt * C_DIM + c0);
            #pragma unroll
            for (int k = 0; k < 4; ++k)
                h[k][tt] += xv.x * wv[0][k] + xv.y * wv[1][k] + xv.z * wv[2][k] + xv.w * wv[3][k];
        }
    }
    #pragma unroll
    for (int k = 0; k < 4; ++k)
        #pragma unroll
        for (int tt = 0; tt < TT; ++tt) {
            float v = h[k][tt];
            h[k][tt] = 0.5f * v * (1.f + erff(v * 0.70710678118f));
        }

    const float* Wp_e = Wproj + (size_t)e * H_DIM * C_DIM;
    float yacc[TT];
    {
        float bp = bproj[(size_t)e * C_DIM + j];
        #pragma unroll
        for (int tt = 0; tt < TT; ++tt) yacc[tt] = bp;
    }
    #pragma unroll
    for (int k = 0; k < 4; ++k) {
        __syncthreads();
        #pragma unroll
        for (int tt = 0; tt < TT; ++tt) hs[tt * C_DIM + j] = h[k][tt];
        __syncthreads();
        for (int h0 = 0; h0 < 256; h0 += 4) {
            float wv[4];
            #pragma unroll
            for (int hi = 0; hi < 4; ++hi)
                wv[hi] = Wp_e[(size_t)(k * 256 + h0 + hi) * C_DIM + j];
            #pragma unroll
            for (int tt = 0; tt < TT; ++tt) {
                float4 hv = *(const float4*)(hs + tt * C_DIM + h0);
                yacc[tt] += hv.x * wv[0] + hv.y * wv[1] + hv.z * wv[2] + hv.w * wv[3];
            }
        }
    }

    __syncthreads();
    #pragma unroll
    for (int tt = 0; tt < TT; ++tt) hs[tt * C_DIM + j] = yacc[tt];
    __syncthreads();

    const float cc0 = cptr[0];
    const int wave = j >> 6, lane = j & 63;
    for (int q = 0; q < 4; ++q) {
        int tt = wave * 4 + q;
        if (tt >= nt) break;
        int tok = stok[tt];
        float s2 = 0.f, sxy = 0.f;
        #pragma unroll
        for (int m = 0; m < 4; ++m) {
            int ccol = lane + 64 * m;
            float yv = hs[tt * C_DIM + ccol];
            float rv = rfp[(size_t)tok * C_DIM + ccol];
            s2 += yv * yv; sxy += rv * yv;
        }
        #pragma unroll
        for (int off = 32; off; off >>= 1) {
            s2  += __shfl_down(s2, off);
            sxy += __shfl_down(sxy, off);
        }
        if (lane == 0) {
            float ref2 = ref2p[tok];
            float sf = 2.f / (1.f + cc0 * ref2);
            float vn = sqrtf(s2);
            float a = sqrtf(cc0 * sf * 0.5f);
            float alpha = (vn > 1e-20f)
                        ? (tanhf(a * vn) / (vn * sqrtf(cc0)))
                        : (a / sqrtf(cc0));
            float axy = alpha * sxy;
            float ay2 = alpha * alpha * s2;
            float A   = 1.f + 2.f * cc0 * axy + cc0 * ay2;
            float Bc  = (1.f - cc0 * ref2) * alpha;
            float den = 1.f + 2.f * cc0 * axy + cc0 * cc0 * ref2 * ay2;
            float wi  = swgt[tt] / den;
            scA[tt] = A * wi;
            scB[tt] = Bc * wi;
        }
    }
    __syncthreads();

    for (int tt = 0; tt < nt; ++tt) {
        int tok = stok[tt];
        float rv = rfp[(size_t)tok * C_DIM + j];
        float yv = hs[tt * C_DIM + j];
        atomicAdd(&out[(size_t)tok * C_DIM + j], scA[tt] * rv + scB[tt] * yv);
    }
}

extern "C" void kernel_launch(void* const* d_in, const int* in_sizes, int n_in,
                              void* d_out, int out_size, void* d_ws, size_t ws_size,
                              hipStream_t stream) {
    (void)in_sizes; (void)n_in; (void)out_size;
    const float* x     = (const float*)d_in[0];
    const float* rfp   = (const float*)d_in[1];
    const float* Wg    = (const float*)d_in[2];
    const float* bg    = (const float*)d_in[3];
    const float* ebias = (const float*)d_in[4];
    const float* Wfc   = (const float*)d_in[5];
    const float* bfc   = (const float*)d_in[6];
    const float* Wproj = (const float*)d_in[7];
    const float* bproj = (const float*)d_in[8];
    const float* cptr  = (const float*)d_in[9];

    float* out = (float*)d_out;                       // [n, C]
    float* rw  = out + (size_t)N_TOK * C_DIM;         // [n, E]

    constexpr size_t OFF_BTOK  = 128;
    constexpr size_t OFF_BWGT  = OFF_BTOK + (size_t)E_DIM * N_TOK * 4;
    constexpr size_t OFF_REF2  = OFF_BWGT + (size_t)E_DIM * N_TOK * 4;
    constexpr size_t OFF_WFC   = ((OFF_REF2 + (size_t)N_TOK * 4 + 255) / 256) * 256;
    constexpr size_t SZ_W      = (size_t)E_DIM * C_DIM * H_DIM * 2;  // 16 MB bf16 each
    constexpr size_t OFF_WPROJ = OFF_WFC + SZ_W;
    constexpr size_t WS_NEEDED = OFF_WPROJ + SZ_W;

    char* ws = (char*)d_ws;
    int*   counts = (int*)ws;
    int*   btok   = (int*)(ws + OFF_BTOK);
    float* bwgt   = (float*)(ws + OFF_BWGT);
    float* ref2   = (float*)(ws + OFF_REF2);

    hipMemsetAsync(counts, 0, E_DIM * sizeof(int), stream);
    hipMemsetAsync(out, 0, (size_t)N_TOK * C_DIM * sizeof(float), stream);

    gate_kernel<<<N_TOK, 256, 0, stream>>>(x, rfp, Wg, bg, ebias,
                                           rw, counts, btok, bwgt, ref2);

    if (ws_size >= WS_NEEDED) {
        ushort_t* WfcF   = (ushort_t*)(ws + OFF_WFC);
        ushort_t* WprojF = (ushort_t*)(ws + OFF_WPROJ);
        wtrans_kernel<<<8192, 256, 0, stream>>>(Wfc, Wproj, WfcF, WprojF);
        dim3 grid(N_TOK / MT, E_DIM);
        expert_mfma<<<grid, 256, 0, stream>>>(x, rfp, WfcF, WprojF, bfc, bproj,
                                              cptr, ref2, counts, btok, bwgt, out);
    } else {
        dim3 grid(E_DIM, N_TOK / TT);
        expert_kernel<<<grid, 256, 0, stream>>>(x, rfp, Wfc, bfc, Wproj, bproj,
                                                cptr, ref2, counts, btok, bwgt, out);
    }
}

// Round 3
// 321.282 us; speedup vs baseline: 8.6634x; 1.5329x over previous
//
#include <hip/hip_runtime.h>
#include <math.h>

#define N_TOK 4096
#define C_DIM 256
#define G_DIM 31
#define E_DIM 32
#define H_DIM 1024
#define TT    16   // fallback tile
#define MT    32   // mfma tile tokens

typedef unsigned short ushort_t;
typedef unsigned int uint_t;
typedef __attribute__((ext_vector_type(8))) short bfrag;
typedef __attribute__((ext_vector_type(4))) float f32x4;
typedef __attribute__((ext_vector_type(8))) unsigned short ushort8;

__device__ __forceinline__ ushort_t f2bf(float f) {
    uint_t u = __float_as_uint(f);
    uint_t r = (u + 0x7fffu + ((u >> 16) & 1u)) >> 16;
    return (ushort_t)r;
}

__device__ __forceinline__ float gelu_f(float v) {
    float u = 0.7978845608f * fmaf(0.044715f * v * v, v, v);
    float t = __expf(-2.f * u);
    return 0.5f * v * (1.f + (1.f - t) / (1.f + t));
}

// ---------------- gate kernel: 1 block (256 thr) per token ----------------
// btok entries are packed: tok | (slot << 12), slot in 0..3
__global__ __launch_bounds__(256) void gate_kernel(
    const float* __restrict__ xf, const float* __restrict__ rfp,
    const float* __restrict__ Wg, const float* __restrict__ bg,
    const float* __restrict__ ebias,
    float* __restrict__ rw_out, int* __restrict__ counts,
    int* __restrict__ btok, float* __restrict__ bwgt,
    float* __restrict__ ref2_out)
{
    const int tok = blockIdx.x;
    const int j = threadIdx.x;
    __shared__ __align__(16) float xs[C_DIM];
    __shared__ float lg[G_DIM];
    __shared__ float wred[4];

    float xv = xf[(size_t)tok * C_DIM + j];
    xs[j] = xv;
    float rv = rfp[(size_t)tok * C_DIM + j];
    float r2 = rv * rv;
    #pragma unroll
    for (int off = 32; off; off >>= 1) r2 += __shfl_down(r2, off);
    if ((j & 63) == 0) wred[j >> 6] = r2;
    __syncthreads();

    const int g = j >> 3, sub = j & 7;
    if (g < G_DIM) {
        float acc = 0.f;
        for (int c = sub; c < C_DIM; c += 8)
            acc += xs[c] * Wg[c * G_DIM + g];
        acc += __shfl_down(acc, 4);
        acc += __shfl_down(acc, 2);
        acc += __shfl_down(acc, 1);
        if (sub == 0) lg[g] = acc + bg[g];
    }
    __syncthreads();

    if (j == 0) {
        float ref2 = wred[0] + wred[1] + wred[2] + wred[3];
        ref2_out[tok] = ref2;

        float m = lg[0];
        #pragma unroll
        for (int g2 = 1; g2 < G_DIM; ++g2) m = fmaxf(m, lg[g2]);
        float p[G_DIM];
        float s = 0.f;
        #pragma unroll
        for (int g2 = 0; g2 < G_DIM; ++g2) { p[g2] = __expf(lg[g2] - m); s += p[g2]; }
        float inv = 1.f / s;
        float bi[G_DIM];
        #pragma unroll
        for (int g2 = 0; g2 < G_DIM; ++g2) bi[g2] = p[g2] * inv + ebias[g2];

        int   idx[3];
        float val[3];
        #pragma unroll
        for (int t = 0; t < 3; ++t) {
            int   bidx = 0;
            float bv = -1e30f;
            for (int g2 = 0; g2 < G_DIM; ++g2)
                if (bi[g2] > bv) { bv = bi[g2]; bidx = g2; }
            idx[t] = bidx; val[t] = bv; bi[bidx] = -1e30f;
        }
        float vs = val[0] + val[1] + val[2];
        float w[3];
        #pragma unroll
        for (int t = 0; t < 3; ++t) w[t] = (val[t] / vs) * 0.75f;

        float r32[E_DIM];
        #pragma unroll
        for (int e = 0; e < E_DIM; ++e) r32[e] = 0.f;
        r32[0] = 0.25f;
        #pragma unroll
        for (int t = 0; t < 3; ++t) r32[idx[t] + 1] = w[t];
        for (int e = 0; e < E_DIM; ++e) rw_out[(size_t)tok * E_DIM + e] = r32[e];

        int slot = atomicAdd(&counts[0], 1);
        btok[slot] = tok;              // slot id 0
        bwgt[slot] = 0.25f;
        #pragma unroll
        for (int t = 0; t < 3; ++t) {
            int e = idx[t] + 1;
            slot = atomicAdd(&counts[e], 1);
            btok[(size_t)e * N_TOK + slot] = tok | ((t + 1) << 12);
            bwgt[(size_t)e * N_TOK + slot] = w[t];
        }
    }
}

// ---------------- weight transform: fp32 -> bf16 fragment-linear blocks ----------------
__global__ __launch_bounds__(256) void wtrans_kernel(
    const float* __restrict__ Wfc, const float* __restrict__ Wproj,
    ushort_t* __restrict__ WfcF, ushort_t* __restrict__ WprojF)
{
    int fb = blockIdx.x * 4 + (threadIdx.x >> 6);
    int lane = threadIdx.x & 63;
    ushort8 pv;
    if (fb < E_DIM * 8 * 64) {
        int e = fb >> 9, kt = (fb >> 6) & 7, nt = fb & 63;
        const float* src = Wfc + ((size_t)e << 18);
        int k0 = kt * 32 + (lane >> 4) * 8, n = nt * 16 + (lane & 15);
        #pragma unroll
        for (int j = 0; j < 8; ++j)
            pv[j] = f2bf(src[((size_t)(k0 + j) << 10) + n]);
        *(ushort8*)(WfcF + ((size_t)fb * 64 + lane) * 8) = pv;
    } else {
        int b2 = fb - E_DIM * 8 * 64;
        int e = b2 >> 9, kt = (b2 >> 4) & 31, nt = b2 & 15;
        const float* src = Wproj + ((size_t)e << 18);
        int k0 = kt * 32 + (lane >> 4) * 8, n = nt * 16 + (lane & 15);
        #pragma unroll
        for (int j = 0; j < 8; ++j)
            pv[j] = f2bf(src[((size_t)(k0 + j) << 8) + n]);
        *(ushort8*)(WprojF + ((size_t)b2 * 64 + lane) * 8) = pv;
    }
}

// ---------------- MFMA expert kernel: 32 tokens x 1 expert per block ----------------
// part != nullptr: race-free coalesced stores to part[slot][tok][c]
// part == nullptr: coalesced atomicAdd into out
__global__ __launch_bounds__(256) void expert_mfma(
    const float* __restrict__ xf, const float* __restrict__ rfp,
    const ushort_t* __restrict__ WfcF, const ushort_t* __restrict__ WprojF,
    const float* __restrict__ bfc, const float* __restrict__ bproj,
    const float* __restrict__ cptr, const float* __restrict__ ref2p,
    const int* __restrict__ counts, const int* __restrict__ btok,
    const float* __restrict__ bwgt, float* __restrict__ part,
    float* __restrict__ out)
{
    const int e = blockIdx.y;
    const int cnt = counts[e];
    const int base = blockIdx.x * MT;
    if (base >= cnt) return;
    const int ntk = min(MT, cnt - base);
    const int tid = threadIdx.x;
    const int lane = tid & 63;
    const int w = tid >> 6;

    __shared__ __align__(16) ushort_t hfrag[MT * H_DIM];  // 64 KB
    __shared__ int   stok[MT];
    __shared__ int   sslot[MT];
    __shared__ float swgt[MT];
    __shared__ float scA[MT], scB[MT];

    if (tid < MT) {
        bool v = (base + tid) < cnt;
        int pk = btok[(size_t)e * N_TOK + (v ? base + tid : base)];
        stok[tid]  = pk & 0xFFF;
        sslot[tid] = pk >> 12;
        swgt[tid]  = v ? bwgt[(size_t)e * N_TOK + base + tid] : 0.f;
    }
    __syncthreads();

    // ---- stage x into phase-1 A-fragment layout ----
    {
        const int r  = tid >> 3;
        const int c0 = (tid & 7) * 32;
        const int mt = r >> 4, rr = r & 15;
        const int kt = c0 >> 5;
        const bool valid = (r < ntk);
        const float* xrow = xf + (size_t)stok[r] * C_DIM;
        #pragma unroll
        for (int q = 0; q < 4; ++q) {
            ushort8 pv;
            #pragma unroll
            for (int j = 0; j < 8; ++j) {
                float xv = valid ? xrow[c0 + q * 8 + j] : 0.f;
                pv[j] = f2bf(xv);
            }
            *(ushort8*)(hfrag + (size_t)((mt * 8 + kt) * 64 + (rr + 16 * q)) * 8) = pv;
        }
    }
    __syncthreads();

    // ---- preload A fragments ----
    bfrag afr[2][8];
    #pragma unroll
    for (int mt = 0; mt < 2; ++mt)
        #pragma unroll
        for (int kt = 0; kt < 8; ++kt)
            afr[mt][kt] = *(const bfrag*)(hfrag + (size_t)((mt * 8 + kt) * 64 + lane) * 8);
    __syncthreads();

    // ---- phase 1: h = gelu(x @ Wfc + bfc), written as phase-2 A-frags ----
    {
        const ushort_t* wbase = WfcF + (size_t)e * 512 * 512;
        bfrag bcur[8], bnxt[8];
        {
            int n1g = w * 16;
            #pragma unroll
            for (int kt = 0; kt < 8; ++kt)
                bcur[kt] = *(const bfrag*)(wbase + (size_t)(kt * 64 + n1g) * 512 + lane * 8);
        }
        for (int n1 = 0; n1 < 16; ++n1) {
            const int n1gc = w * 16 + n1;
            if (n1 < 15) {
                #pragma unroll
                for (int kt = 0; kt < 8; ++kt)
                    bnxt[kt] = *(const bfrag*)(wbase + (size_t)(kt * 64 + n1gc + 1) * 512 + lane * 8);
            }
            const int hcol = n1gc * 16 + (lane & 15);
            const float bv = bfc[e * H_DIM + hcol];
            f32x4 acc0 = {bv, bv, bv, bv}, acc1 = {bv, bv, bv, bv};
            #pragma unroll
            for (int kt = 0; kt < 8; ++kt) {
                acc0 = __builtin_amdgcn_mfma_f32_16x16x32_bf16(afr[0][kt], bcur[kt], acc0, 0, 0, 0);
                acc1 = __builtin_amdgcn_mfma_f32_16x16x32_bf16(afr[1][kt], bcur[kt], acc1, 0, 0, 0);
            }
            const int jj   = hcol & 7;
            const int grp  = (hcol & 31) >> 3;
            const int kth  = hcol >> 5;
            const int rb   = (lane >> 4) * 4;
            #pragma unroll
            for (int mt = 0; mt < 2; ++mt) {
                f32x4 a = mt ? acc1 : acc0;
                #pragma unroll
                for (int r = 0; r < 4; ++r) {
                    float g = gelu_f(a[r]);
                    int lanep = (rb + r) + 16 * grp;
                    hfrag[(size_t)((mt * 32 + kth) * 64 + lanep) * 8 + jj] = f2bf(g);
                }
            }
            if (n1 < 15) {
                #pragma unroll
                for (int kt = 0; kt < 8; ++kt) bcur[kt] = bnxt[kt];
            }
        }
    }
    __syncthreads();

    // ---- phase 2: y = h @ Wproj + bproj ----
    f32x4 yac[2][4];
    #pragma unroll
    for (int mt = 0; mt < 2; ++mt)
        #pragma unroll
        for (int q = 0; q < 4; ++q) {
            int ccol = (w * 4 + q) * 16 + (lane & 15);
            float bv = bproj[e * C_DIM + ccol];
            yac[mt][q] = {bv, bv, bv, bv};
        }
    {
        const ushort_t* wbase = WprojF + (size_t)e * 512 * 512;
        #pragma unroll 2
        for (int kt = 0; kt < 32; ++kt) {
            bfrag a0 = *(const bfrag*)(hfrag + (size_t)((kt)      * 64 + lane) * 8);
            bfrag a1 = *(const bfrag*)(hfrag + (size_t)((32 + kt) * 64 + lane) * 8);
            #pragma unroll
            for (int q = 0; q < 4; ++q) {
                bfrag bf = *(const bfrag*)(wbase + (size_t)(kt * 16 + (w * 4 + q)) * 512 + lane * 8);
                yac[0][q] = __builtin_amdgcn_mfma_f32_16x16x32_bf16(a0, bf, yac[0][q], 0, 0, 0);
                yac[1][q] = __builtin_amdgcn_mfma_f32_16x16x32_bf16(a1, bf, yac[1][q], 0, 0, 0);
            }
        }
    }
    __syncthreads();

    // ---- write y (f32) into LDS natural layout [32][264] (reuse hfrag) ----
    float* ynat = (float*)hfrag;   // 32*264*4 = 33792 B
    #pragma unroll
    for (int mt = 0; mt < 2; ++mt)
        #pragma unroll
        for (int q = 0; q < 4; ++q) {
            int ccol = (w * 4 + q) * 16 + (lane & 15);
            #pragma unroll
            for (int r = 0; r < 4; ++r) {
                int tt = mt * 16 + (lane >> 4) * 4 + r;
                ynat[tt * 264 + ccol] = yac[mt][q][r];
            }
        }
    __syncthreads();

    // ---- expmap coefficients: one wave per 8 tokens, lane = column group ----
    {
        const float cc0 = cptr[0];
        for (int i = 0; i < 8; ++i) {
            int tt = w * 8 + i;
            if (tt >= ntk) break;
            const float* yrow = ynat + tt * 264;
            const float* rrow = rfp + (size_t)stok[tt] * C_DIM;
            float s2 = 0.f, sxy = 0.f;
            #pragma unroll
            for (int m = 0; m < 4; ++m) {
                float yv = yrow[lane + 64 * m];
                float rv = rrow[lane + 64 * m];
                s2  = fmaf(yv, yv, s2);
                sxy = fmaf(rv, yv, sxy);
            }
            #pragma unroll
            for (int off = 32; off; off >>= 1) {
                s2  += __shfl_down(s2, off);
                sxy += __shfl_down(sxy, off);
            }
            if (lane == 0) {
                float ref2 = ref2p[stok[tt]];
                float sf = 2.f / (1.f + cc0 * ref2);
                float vn = sqrtf(s2);
                float aa = sqrtf(cc0 * sf * 0.5f);
                float alpha = (vn > 1e-20f)
                            ? (tanhf(aa * vn) / (vn * sqrtf(cc0)))
                            : (aa / sqrtf(cc0));
                float axy = alpha * sxy;
                float ay2 = alpha * alpha * s2;
                float A   = 1.f + 2.f * cc0 * axy + cc0 * ay2;
                float Bc  = (1.f - cc0 * ref2) * alpha;
                float den = 1.f + 2.f * cc0 * axy + cc0 * cc0 * ref2 * ay2;
                float wi  = swgt[tt] / den;
                scA[tt] = A * wi;
                scB[tt] = Bc * wi;
            }
        }
    }
    __syncthreads();

    // ---- final write: column-per-thread, fully coalesced ----
    if (part != nullptr) {
        for (int tt = 0; tt < ntk; ++tt) {
            int tok = stok[tt];
            float rv = rfp[(size_t)tok * C_DIM + tid];
            float v = fmaf(scA[tt], rv, scB[tt] * ynat[tt * 264 + tid]);
            part[((size_t)sslot[tt] * N_TOK + tok) * C_DIM + tid] = v;
        }
    } else {
        for (int tt = 0; tt < ntk; ++tt) {
            int tok = stok[tt];
            float rv = rfp[(size_t)tok * C_DIM + tid];
            float v = fmaf(scA[tt], rv, scB[tt] * ynat[tt * 264 + tid]);
            atomicAdd(&out[(size_t)tok * C_DIM + tid], v);
        }
    }
}

// ---------------- combine: out = sum of 4 part slots ----------------
__global__ __launch_bounds__(256) void combine_kernel(
    const float* __restrict__ part, float* __restrict__ out)
{
    const size_t NC = (size_t)N_TOK * C_DIM;
    size_t idx = (size_t)blockIdx.x * 256 + threadIdx.x;
    out[idx] = (part[idx] + part[idx + NC]) + (part[idx + 2 * NC] + part[idx + 3 * NC]);
}

// ---------------- fallback fp32 expert kernel ----------------
__global__ __launch_bounds__(256) void expert_kernel(
    const float* __restrict__ xf, const float* __restrict__ rfp,
    const float* __restrict__ Wfc, const float* __restrict__ bfc,
    const float* __restrict__ Wproj, const float* __restrict__ bproj,
    const float* __restrict__ cptr, const float* __restrict__ ref2p,
    const int* __restrict__ counts, const int* __restrict__ btok,
    const float* __restrict__ bwgt, float* __restrict__ out)
{
    const int e = blockIdx.x;
    const int cnt = counts[e];
    const int base = blockIdx.y * TT;
    if (base >= cnt) return;
    const int nt = min(TT, cnt - base);
    const int j = threadIdx.x;

    __shared__ __align__(16) float xs[TT * C_DIM];
    __shared__ __align__(16) float hs[TT * C_DIM];
    __shared__ int   stok[TT];
    __shared__ float swgt[TT];
    __shared__ float scA[TT], scB[TT];

    if (j < nt) {
        stok[j] = btok[(size_t)e * N_TOK + base + j] & 0xFFF;
        swgt[j] = bwgt[(size_t)e * N_TOK + base + j];
    }
    __syncthreads();
    for (int t = 0; t < nt; ++t) xs[t * C_DIM + j] = xf[(size_t)stok[t] * C_DIM + j];
    for (int t = nt; t < TT; ++t) xs[t * C_DIM + j] = 0.f;
    __syncthreads();

    const float* Wfc_e = Wfc + (size_t)e * C_DIM * H_DIM;
    float h[4][TT];
    {
        float bk[4];
        #pragma unroll
        for (int k = 0; k < 4; ++k) bk[k] = bfc[(size_t)e * H_DIM + j + k * 256];
        #pragma unroll
        for (int k = 0; k < 4; ++k)
            #pragma unroll
            for (int tt = 0; tt < TT; ++tt) h[k][tt] = bk[k];
    }
    for (int c0 = 0; c0 < C_DIM; c0 += 4) {
        float wv[4][4];
        #pragma unroll
        for (int ci = 0; ci < 4; ++ci) {
            const float* wp = Wfc_e + (size_t)(c0 + ci) * H_DIM + j;
            wv[ci][0] = wp[0]; wv[ci][1] = wp[256]; wv[ci][2] = wp[512]; wv[ci][3] = wp[768];
        }
        #pragma unroll
        for (int tt = 0; tt < TT; ++tt) {
            float4 xv = *(const float4*)(xs + tt * C_DIM + c0);
            #pragma unroll
            for (int k = 0; k < 4; ++k)
                h[k][tt] += xv.x * wv[0][k] + xv.y * wv[1][k] + xv.z * wv[2][k] + xv.w * wv[3][k];
        }
    }
    #pragma unroll
    for (int k = 0; k < 4; ++k)
        #pragma unroll
        for (int tt = 0; tt < TT; ++tt) {
            float v = h[k][tt];
            h[k][tt] = 0.5f * v * (1.f + erff(v * 0.70710678118f));
        }

    const float* Wp_e = Wproj + (size_t)e * H_DIM * C_DIM;
    float yacc[TT];
    {
        float bp = bproj[(size_t)e * C_DIM + j];
        #pragma unroll
        for (int tt = 0; tt < TT; ++tt) yacc[tt] = bp;
    }
    #pragma unroll
    for (int k = 0; k < 4; ++k) {
        __syncthreads();
        #pragma unroll
        for (int tt = 0; tt < TT; ++tt) hs[tt * C_DIM + j] = h[k][tt];
        __syncthreads();
        for (int h0 = 0; h0 < 256; h0 += 4) {
            float wv[4];
            #pragma unroll
            for (int hi = 0; hi < 4; ++hi)
                wv[hi] = Wp_e[(size_t)(k * 256 + h0 + hi) * C_DIM + j];
            #pragma unroll
            for (int tt = 0; tt < TT; ++tt) {
                float4 hv = *(const float4*)(hs + tt * C_DIM + h0);
                yacc[tt] += hv.x * wv[0] + hv.y * wv[1] + hv.z * wv[2] + hv.w * wv[3];
            }
        }
    }

    __syncthreads();
    #pragma unroll
    for (int tt = 0; tt < TT; ++tt) hs[tt * C_DIM + j] = yacc[tt];
    __syncthreads();

    const float cc0 = cptr[0];
    const int wave = j >> 6, lane = j & 63;
    for (int q = 0; q < 4; ++q) {
        int tt = wave * 4 + q;
        if (tt >= nt) break;
        int tok = stok[tt];
        float s2 = 0.f, sxy = 0.f;
        #pragma unroll
        for (int m = 0; m < 4; ++m) {
            int ccol = lane + 64 * m;
            float yv = hs[tt * C_DIM + ccol];
            float rv = rfp[(size_t)tok * C_DIM + ccol];
            s2 += yv * yv; sxy += rv * yv;
        }
        #pragma unroll
        for (int off = 32; off; off >>= 1) {
            s2  += __shfl_down(s2, off);
            sxy += __shfl_down(sxy, off);
        }
        if (lane == 0) {
            float ref2 = ref2p[tok];
            float sf = 2.f / (1.f + cc0 * ref2);
            float vn = sqrtf(s2);
            float a = sqrtf(cc0 * sf * 0.5f);
            float alpha = (vn > 1e-20f)
                        ? (tanhf(a * vn) / (vn * sqrtf(cc0)))
                        : (a / sqrtf(cc0));
            float axy = alpha * sxy;
            float ay2 = alpha * alpha * s2;
            float A   = 1.f + 2.f * cc0 * axy + cc0 * ay2;
            float Bc  = (1.f - cc0 * ref2) * alpha;
            float den = 1.f + 2.f * cc0 * axy + cc0 * cc0 * ref2 * ay2;
            float wi  = swgt[tt] / den;
            scA[tt] = A * wi;
            scB[tt] = Bc * wi;
        }
    }
    __syncthreads();

    for (int tt = 0; tt < nt; ++tt) {
        int tok = stok[tt];
        float rv = rfp[(size_t)tok * C_DIM + j];
        float yv = hs[tt * C_DIM + j];
        atomicAdd(&out[(size_t)tok * C_DIM + j], scA[tt] * rv + scB[tt] * yv);
    }
}

extern "C" void kernel_launch(void* const* d_in, const int* in_sizes, int n_in,
                              void* d_out, int out_size, void* d_ws, size_t ws_size,
                              hipStream_t stream) {
    (void)in_sizes; (void)n_in; (void)out_size;
    const float* x     = (const float*)d_in[0];
    const float* rfp   = (const float*)d_in[1];
    const float* Wg    = (const float*)d_in[2];
    const float* bg    = (const float*)d_in[3];
    const float* ebias = (const float*)d_in[4];
    const float* Wfc   = (const float*)d_in[5];
    const float* bfc   = (const float*)d_in[6];
    const float* Wproj = (const float*)d_in[7];
    const float* bproj = (const float*)d_in[8];
    const float* cptr  = (const float*)d_in[9];

    float* out = (float*)d_out;                       // [n, C]
    float* rw  = out + (size_t)N_TOK * C_DIM;         // [n, E]

    constexpr size_t OFF_BTOK  = 128;
    constexpr size_t OFF_BWGT  = OFF_BTOK + (size_t)E_DIM * N_TOK * 4;
    constexpr size_t OFF_REF2  = OFF_BWGT + (size_t)E_DIM * N_TOK * 4;
    constexpr size_t OFF_WFC   = ((OFF_REF2 + (size_t)N_TOK * 4 + 255) / 256) * 256;
    constexpr size_t SZ_W      = (size_t)E_DIM * C_DIM * H_DIM * 2;  // 16 MB bf16 each
    constexpr size_t OFF_WPROJ = OFF_WFC + SZ_W;
    constexpr size_t OFF_PART  = OFF_WPROJ + SZ_W;
    constexpr size_t SZ_PART   = (size_t)4 * N_TOK * C_DIM * 4;      // 16 MB
    constexpr size_t WS_MFMA   = OFF_PART;
    constexpr size_t WS_FULL   = OFF_PART + SZ_PART;

    char* ws = (char*)d_ws;
    int*   counts = (int*)ws;
    int*   btok   = (int*)(ws + OFF_BTOK);
    float* bwgt   = (float*)(ws + OFF_BWGT);
    float* ref2   = (float*)(ws + OFF_REF2);

    hipMemsetAsync(counts, 0, E_DIM * sizeof(int), stream);

    gate_kernel<<<N_TOK, 256, 0, stream>>>(x, rfp, Wg, bg, ebias,
                                           rw, counts, btok, bwgt, ref2);

    if (ws_size >= WS_FULL) {
        // race-free partials path: no atomics, no out memset
        ushort_t* WfcF   = (ushort_t*)(ws + OFF_WFC);
        ushort_t* WprojF = (ushort_t*)(ws + OFF_WPROJ);
        float*    part   = (float*)(ws + OFF_PART);
        wtrans_kernel<<<8192, 256, 0, stream>>>(Wfc, Wproj, WfcF, WprojF);
        dim3 grid(N_TOK / MT, E_DIM);
        expert_mfma<<<grid, 256, 0, stream>>>(x, rfp, WfcF, WprojF, bfc, bproj,
                                              cptr, ref2, counts, btok, bwgt, part, out);
        combine_kernel<<<(N_TOK * C_DIM) / 256, 256, 0, stream>>>(part, out);
    } else if (ws_size >= WS_MFMA) {
        hipMemsetAsync(out, 0, (size_t)N_TOK * C_DIM * sizeof(float), stream);
        ushort_t* WfcF   = (ushort_t*)(ws + OFF_WFC);
        ushort_t* WprojF = (ushort_t*)(ws + OFF_WPROJ);
        wtrans_kernel<<<8192, 256, 0, stream>>>(Wfc, Wproj, WfcF, WprojF);
        dim3 grid(N_TOK / MT, E_DIM);
        expert_mfma<<<grid, 256, 0, stream>>>(x, rfp, WfcF, WprojF, bfc, bproj,
                                              cptr, ref2, counts, btok, bwgt, nullptr, out);
    } else {
        hipMemsetAsync(out, 0, (size_t)N_TOK * C_DIM * sizeof(float), stream);
        dim3 grid(E_DIM, N_TOK / TT);
        expert_kernel<<<grid, 256, 0, stream>>>(x, rfp, Wfc, bfc, Wproj, bproj,
                                                cptr, ref2, counts, btok, bwgt, out);
    }
}